// Round 11
// baseline (41.305 us; speedup 1.0000x reference)
//
#include <hip/hip_runtime.h>

#define Ndim 128
#define Cdim 3
#define Hdim 256
#define Wdim 256
#define HW (Hdim * Wdim)
#define MAXNORM_F 5.371920351148152f

#define LCOLS 56     // staged window width (14 x 16B chunks)
#define LROWS 48     // staged window max rows (guard rn <= 48)
#define LBUF  (LCOLS * LROWS)   // 2688 dwords = 10752 B per channel buffer

typedef float vf2 __attribute__((ext_vector_type(2)));
typedef unsigned int uint32;

__device__ __forceinline__ void mm3f(const float a[3][3], const float b[3][3], float c[3][3]) {
    #pragma unroll
    for (int i = 0; i < 3; ++i)
        #pragma unroll
        for (int j = 0; j < 3; ++j) {
            float s = 0.0f;
            #pragma unroll
            for (int k = 0; k < 3; ++k) s = fmaf(a[i][k], b[k][j], s);
            c[i][j] = s;
        }
}

// One thread per batch element: expm of padded 3x3 affine matrix (fp32 Pade-13).
__global__ void expm_kernel(const float* __restrict__ theta, float* __restrict__ thOut) {
    int n = blockIdx.x * blockDim.x + threadIdx.x;
    if (n >= Ndim) return;

    const float b[14] = {6.476475253248e+16f, 3.238237626624e+16f, 7771770303897600.0f,
                         1187353796428800.0f, 129060195264000.0f, 10559470521600.0f,
                         670442572800.0f, 33522128640.0f, 1323241920.0f, 40840800.0f,
                         960960.0f, 16380.0f, 182.0f, 1.0f};

    float A[3][3];
    #pragma unroll
    for (int j = 0; j < 3; ++j) {
        A[0][j] = theta[n * 6 + j];
        A[1][j] = theta[n * 6 + 3 + j];
        A[2][j] = 0.0f;
    }

    float fro2 = 0.0f;
    #pragma unroll
    for (int i = 0; i < 3; ++i)
        #pragma unroll
        for (int j = 0; j < 3; ++j) fro2 = fmaf(A[i][j], A[i][j], fro2);
    float fro = sqrtf(fro2);

    float nsq = fmaxf(0.0f, ceilf(log2f(fro / MAXNORM_F)));
    int k = (int)nsq;
    float sc = exp2f(-nsq);
    #pragma unroll
    for (int i = 0; i < 3; ++i)
        #pragma unroll
        for (int j = 0; j < 3; ++j) A[i][j] *= sc;

    float A2[3][3], A4[3][3], A6[3][3], P[3][3], Wm[3][3], T[3][3], U[3][3], V[3][3];
    mm3f(A, A, A2);
    mm3f(A2, A2, A4);
    mm3f(A4, A2, A6);

    #pragma unroll
    for (int i = 0; i < 3; ++i)
        #pragma unroll
        for (int j = 0; j < 3; ++j)
            P[i][j] = b[13] * A6[i][j] + b[11] * A4[i][j] + b[9] * A2[i][j];
    mm3f(A6, P, T);
    #pragma unroll
    for (int i = 0; i < 3; ++i)
        #pragma unroll
        for (int j = 0; j < 3; ++j)
            Wm[i][j] = T[i][j] + b[7] * A6[i][j] + b[5] * A4[i][j] + b[3] * A2[i][j]
                       + (i == j ? b[1] : 0.0f);
    mm3f(A, Wm, U);

    #pragma unroll
    for (int i = 0; i < 3; ++i)
        #pragma unroll
        for (int j = 0; j < 3; ++j)
            P[i][j] = b[12] * A6[i][j] + b[10] * A4[i][j] + b[8] * A2[i][j];
    mm3f(A6, P, T);
    #pragma unroll
    for (int i = 0; i < 3; ++i)
        #pragma unroll
        for (int j = 0; j < 3; ++j)
            V[i][j] = T[i][j] + b[6] * A6[i][j] + b[4] * A4[i][j] + b[2] * A2[i][j]
                      + (i == j ? b[0] : 0.0f);

    float M[3][6];
    #pragma unroll
    for (int i = 0; i < 3; ++i)
        #pragma unroll
        for (int j = 0; j < 3; ++j) {
            M[i][j]     = U[i][j] + V[i][j];
            M[i][j + 3] = V[i][j] - U[i][j];
        }
    #pragma unroll
    for (int col = 0; col < 3; ++col) {
        int piv = col;
        float best = fabsf(M[col][col]);
        for (int r = col + 1; r < 3; ++r) {
            float v = fabsf(M[r][col]);
            if (v > best) { best = v; piv = r; }
        }
        if (piv != col) {
            #pragma unroll
            for (int j = 0; j < 6; ++j) {
                float t = M[col][j]; M[col][j] = M[piv][j]; M[piv][j] = t;
            }
        }
        float inv = 1.0f / M[col][col];
        #pragma unroll
        for (int j = 0; j < 6; ++j) M[col][j] *= inv;
        #pragma unroll
        for (int r = 0; r < 3; ++r) {
            if (r == col) continue;
            float f = M[r][col];
            #pragma unroll
            for (int j = 0; j < 6; ++j) M[r][j] -= f * M[col][j];
        }
    }
    float R[3][3];
    #pragma unroll
    for (int i = 0; i < 3; ++i)
        #pragma unroll
        for (int j = 0; j < 3; ++j) R[i][j] = M[i][j + 3];

    for (int i = 0; i < 16; ++i) {
        if (i < k) {
            float Rn[3][3];
            mm3f(R, R, Rn);
            #pragma unroll
            for (int a = 0; a < 3; ++a)
                #pragma unroll
                for (int c = 0; c < 3; ++c) R[a][c] = Rn[a][c];
        }
    }

    #pragma unroll
    for (int j = 0; j < 3; ++j) {
        thOut[n * 6 + j]     = (float)R[0][j];
        thOut[n * 6 + 3 + j] = (float)R[1][j];
    }
}

// Fused affine_grid + bilinear grid_sample (zeros padding, align_corners=True).
// Block = 32x32 output tile; 256 threads, each a 1-wide x 4-tall strip.
// R11 change: stage ONE CHANNEL at a time into two ping-pong LDS buffers
// ([48 rows][56 cols] fp32, 2 x 10752 B = 21504 B total -> 7 blocks/CU vs 4),
// software-pipelined: stage(c0); bar; stage(c1)||sample(c0); bar;
// stage(c2)||sample(c1); bar; sample(c2). Each barrier's implicit vmcnt(0)
// lands after the previous channel's sampling covered part of the fetch
// latency, and 7 resident blocks/CU overlap the rest. Guards: cn<=52,
// rn<=48 (else exact global-gather fallback; ~1% of images).
__global__ __launch_bounds__(256) void sample_kernel(const float* __restrict__ x,
                                                     const float* __restrict__ th,
                                                     float* __restrict__ out) {
    __shared__ float lds[2][LBUF];

    // 8x8 tiles/image * 128 images = 8192 blocks; bijective XCD swizzle
    const int nwg_per_xcd = 8192 / 8;
    int bid = blockIdx.x;
    int wgid = (bid & 7) * nwg_per_xcd + (bid >> 3);

    int tw  = wgid & 7;
    int thp = (wgid >> 3) & 7;
    int n   = wgid >> 6;

    int tid = threadIdx.x;
    int w  = (tw << 5) + (tid & 31);         // lane-consecutive column
    int h0 = (thp << 5) + ((tid >> 5) << 2); // 4 rows h0..h0+3

    const float* t = th + n * 6;
    float t0 = t[0], t1 = t[1], t2 = t[2], t3 = t[3], t4 = t[4], t5 = t[5];

    float Cx = 127.5f * (t2 - t0 - t1 + 1.0f);
    float Cy = 127.5f * (t5 - t3 - t4 + 1.0f);

    // block-uniform bounding box of sample coords (pad +-1 fp slack, +1 corner)
    float fwA = (float)(tw << 5),  fwB = fwA + 31.0f;
    float fhA = (float)(thp << 5), fhB = fhA + 31.0f;
    float xlo = fminf(fwA * t0, fwB * t0) + fminf(fhA * t1, fhB * t1) + Cx;
    float xhi = fmaxf(fwA * t0, fwB * t0) + fmaxf(fhA * t1, fhB * t1) + Cx;
    float ylo = fminf(fwA * t3, fwB * t3) + fminf(fhA * t4, fhB * t4) + Cy;
    float yhi = fmaxf(fwA * t3, fwB * t3) + fmaxf(fhA * t4, fhB * t4) + Cy;
    int Xlo = (int)floorf(xlo) - 1, Xhi = (int)floorf(xhi) + 2;
    int Ylo = (int)floorf(ylo) - 1, Yhi = (int)floorf(yhi) + 2;
    int cn = Xhi - Xlo + 1;
    int rn = Yhi - Ylo + 1;

    size_t nbase = (size_t)n * Cdim * HW;

    // strip sample coords: px p at (w, h0+p)
    float ixs[4], iys[4];
    float ixb = fmaf((float)w, t0, fmaf((float)h0, t1, Cx));
    float iyb = fmaf((float)w, t3, fmaf((float)h0, t4, Cy));
    #pragma unroll
    for (int p = 0; p < 4; ++p) {
        ixs[p] = fmaf((float)p, t1, ixb);
        iys[p] = fmaf((float)p, t4, iyb);
    }

    bool fast = (cn <= 52) && (rn <= LROWS) && (rn >= 1) && (cn >= 1);

    if (fast) {
        int bxw = (min(max(Xlo, 0), Wdim - LCOLS)) & ~3;  // 16B-aligned base col
        int byw = min(max(Ylo, 0), Hdim - rn);
        int totc = 14 * rn;                               // 16B chunks per channel
        const float* gbase = x + nbase;

        // per-channel staging: chunk k -> row k/14, colchunk k%14, buffer slot k
        auto stage = [&](int ch, int buf) {
            #pragma unroll
            for (int it = 0; it < 3; ++it) {
                int k = (it << 8) + tid;
                if (k < totc) {
                    int row = k / 14;
                    int col = k - row * 14;
                    const float* gp = gbase + (size_t)ch * HW
                                    + ((byw + row) << 8) + bxw + (col << 2);
                    __builtin_amdgcn_global_load_lds(
                        (const __attribute__((address_space(1))) uint32*)gp,
                        (__attribute__((address_space(3))) uint32*)
                            ((uint32*)&lds[buf][0] + ((size_t)k << 2)),
                        16, 0, 0);
                }
            }
        };

        bool interior = (Xlo >= 0) && (Xhi <= Wdim - 1) && (Ylo >= 0) && (Yhi <= Hdim - 1);

        stage(0, 0);

        // precompute per-pixel params while c0 is in flight
        int   basev[4];
        float wx1v[4], wy1v[4];
        if (interior) {
            #pragma unroll
            for (int p = 0; p < 4; ++p) {
                float ix = ixs[p], iy = iys[p];
                float fx = floorf(ix), fy = floorf(iy);
                wx1v[p] = ix - fx;
                wy1v[p] = iy - fy;
                basev[p] = ((int)fy - byw) * LCOLS + ((int)fx - bxw);
            }
        }
        size_t p0 = (size_t)h0 * Wdim + w;

        auto sample_interior = [&](int buf, int c) {
            float* o = out + nbase + (size_t)c * HW + p0;
            #pragma unroll
            for (int p = 0; p < 4; ++p) {
                const float* bp = &lds[buf][basev[p]];
                float v00 = bp[0],     v01 = bp[1];        // -> ds_read2_b32
                float v10 = bp[LCOLS], v11 = bp[LCOLS + 1];
                float wx1 = wx1v[p], wx0 = 1.0f - wx1;
                float wy1 = wy1v[p], wy0 = 1.0f - wy1;
                float top = fmaf(v01, wx1, v00 * wx0);
                float bot = fmaf(v11, wx1, v10 * wx0);
                __builtin_nontemporal_store(fmaf(wy1, bot, wy0 * top),
                                            o + (size_t)p * Wdim);
            }
        };

        auto sample_edge = [&](int buf, int c) {
            float* o = out + nbase + (size_t)c * HW + p0;
            #pragma unroll
            for (int p = 0; p < 4; ++p) {
                float ix = ixs[p], iy = iys[p];
                float fx = floorf(ix), fy = floorf(iy);
                int x0i = (int)fx, y0i = (int)fy;
                float wx1 = ix - fx, wx0 = 1.0f - wx1;
                float wy1 = iy - fy, wy0 = 1.0f - wy1;
                float mx0 = ((unsigned)x0i       < (unsigned)Wdim) ? 1.0f : 0.0f;
                float mx1 = ((unsigned)(x0i + 1) < (unsigned)Wdim) ? 1.0f : 0.0f;
                float my0 = ((unsigned)y0i       < (unsigned)Hdim) ? 1.0f : 0.0f;
                float my1 = ((unsigned)(y0i + 1) < (unsigned)Hdim) ? 1.0f : 0.0f;
                float wxm0 = wx0 * mx0, wxm1 = wx1 * mx1;
                float wym0 = wy0 * my0, wym1 = wy1 * my1;

                // per-corner clamped slots; displaced slot => weight 0
                int lx0 = min(max(x0i - bxw, 0), LCOLS - 1);
                int lx1 = min(max(x0i + 1 - bxw, 0), LCOLS - 1);
                int ly0 = min(max(y0i - byw, 0), rn - 1);
                int ly1 = min(max(y0i + 1 - byw, 0), rn - 1);
                const float* B = &lds[buf][0];
                float v00 = B[ly0 * LCOLS + lx0], v01 = B[ly0 * LCOLS + lx1];
                float v10 = B[ly1 * LCOLS + lx0], v11 = B[ly1 * LCOLS + lx1];
                float top = fmaf(v01, wxm1, v00 * wxm0);
                float bot = fmaf(v11, wxm1, v10 * wxm0);
                __builtin_nontemporal_store(fmaf(wym1, bot, wym0 * top),
                                            o + (size_t)p * Wdim);
            }
        };

        __syncthreads();              // waits c0 (compiler vmcnt drain)
        stage(1, 1);                  // issue c1 while sampling c0
        if (interior) sample_interior(0, 0); else sample_edge(0, 0);
        __syncthreads();              // waits c1
        stage(2, 0);                  // issue c2 while sampling c1
        if (interior) sample_interior(1, 1); else sample_edge(1, 1);
        __syncthreads();              // waits c2
        if (interior) sample_interior(0, 2); else sample_edge(0, 2);
    } else {
        // exact fallback: per-pixel global gathers (block-uniform branch)
        const float* img0 = x + nbase;
        #pragma unroll
        for (int p = 0; p < 4; ++p) {
            float ix = ixs[p], iy = iys[p];
            float fx = floorf(ix), fy = floorf(iy);
            int ix0 = (int)fx, iy0 = (int)fy;
            float wx1 = ix - fx, wx0 = 1.0f - wx1;
            float wy1 = iy - fy, wy0 = 1.0f - wy1;
            float mx0 = ((unsigned)ix0       < (unsigned)Wdim) ? 1.0f : 0.0f;
            float mx1 = ((unsigned)(ix0 + 1) < (unsigned)Wdim) ? 1.0f : 0.0f;
            float my0 = ((unsigned)iy0       < (unsigned)Hdim) ? 1.0f : 0.0f;
            float my1 = ((unsigned)(iy0 + 1) < (unsigned)Hdim) ? 1.0f : 0.0f;
            int xc0 = min(max(ix0, 0), Wdim - 1);
            int xc1 = min(max(ix0 + 1, 0), Wdim - 1);
            int yc0 = min(max(iy0, 0), Hdim - 1);
            int yc1 = min(max(iy0 + 1, 0), Hdim - 1);
            float w00 = wy0 * wx0 * my0 * mx0;
            float w01 = wy0 * wx1 * my0 * mx1;
            float w10 = wy1 * wx0 * my1 * mx0;
            float w11 = wy1 * wx1 * my1 * mx1;
            int o00 = yc0 * Wdim + xc0, o01 = yc0 * Wdim + xc1;
            int o10 = yc1 * Wdim + xc0, o11 = yc1 * Wdim + xc1;
            #pragma unroll
            for (int c = 0; c < Cdim; ++c) {
                const float* img = img0 + (size_t)c * HW;
                float r = fmaf(img[o00], w00, fmaf(img[o01], w01,
                          fmaf(img[o10], w10, img[o11] * w11)));
                out[nbase + (size_t)c * HW + (size_t)(h0 + p) * Wdim + w] = r;
            }
        }
    }
}

extern "C" void kernel_launch(void* const* d_in, const int* in_sizes, int n_in,
                              void* d_out, int out_size, void* d_ws, size_t ws_size,
                              hipStream_t stream) {
    const float* x     = (const float*)d_in[0];
    const float* theta = (const float*)d_in[1];
    float* out = (float*)d_out;
    float* th  = (float*)d_ws;  // 128*6 floats of scratch

    expm_kernel<<<1, 128, 0, stream>>>(theta, th);

    int nblocks = 8192;
    sample_kernel<<<nblocks, 256, 0, stream>>>(x, th, out);
}